// Round 11
// baseline (54.301 us; speedup 1.0000x reference)
//
#include <hip/hip_runtime.h>
#include <math.h>

#define RG 61
#define CG 61
#define NP 3721           // RG*CG
#define NSEG 3722         // NP+1
#define NCLS 10
#define THRESHV 0.7f
#define BIGI 0x3FFFFFFF

#define NKQ 16            // blocks per output row; block covers 4 window rows
#define NBLK (RG*NKQ)     // 976
#define CHS 50            // chunk stride (floats): even -> b64-aligned reads
#define ROWF (64*CHS)     // 3200 floats per staged row
#define PROW 610          // part row: 61 cells x 10 classes

// ---------------------------------------------------------------------------
// Kernel 1: partial logits, "wave-uniform W" scheme.
// Block (r,kq) covers window rows 4kq..4kq+3; wave wv owns row wr=4kq+wv and
// iterates its 96 k-pairs. All 64 lanes of a wave share one k-pair -> the 20
// W floats are WAVE-UNIFORM -> s_load into SGPRs (zero LDS traffic for W),
// consumed as v_fmac_f32 vacc, sW, vx. Lane = patch column c (61 used).
// Img rows staged in LDS chunked [ch][CHS=50]: read addr = 50*cx + uniform
// (even) -> one aligned ds_read_b64 per pair, ~min-cycle banking.
// Per pair: 20 FMA + 1 ds_read_b64 + 5 s_load_dwordx4 (offsets fold to imm).
// 51.2KB LDS -> 3 blocks/CU. No cross-wave reduce: each wave stores its own
// part row (61x10) directly.
// ---------------------------------------------------------------------------
__global__ __launch_bounds__(256, 3) void wod_logits_part(
    const float* __restrict__ img,   // (1024,1024,3)
    const float* __restrict__ W,     // (12288,10)
    float* __restrict__ part)        // (61*64, 610)
{
    __shared__ float simg[4 * ROWF]; // 51200 B

    const int tid = threadIdx.x;
    // bijective XCD swizzle: 976 = 8*122
    const int o  = (blockIdx.x & 7) * 122 + (blockIdx.x >> 3);
    const int r  = o >> 4;           // output row  [0,61)
    const int kq = o & 15;           // row-quad    [0,16)
    const int R0 = 16 * r + 4 * kq;  // first image row (<=1023)

    // ---- stage 4 image rows: coalesced float4 global, float2 LDS writes ----
    for (int u = tid; u < 3072; u += 256) {
        const int row = u / 768;
        const int v   = u - row * 768;
        const int p0  = v * 4;
        const float4 x4 = *(const float4*)(img + (size_t)(R0 + row) * 3072 + p0);
        const int ch = p0 / 48;
        const int q  = p0 - ch * 48;        // 0..44, never crosses chunk
        float* d = simg + row * ROWF + ch * CHS + q;   // even -> 8B aligned
        *(float2*)d       = make_float2(x4.x, x4.y);
        *(float2*)(d + 2) = make_float2(x4.z, x4.w);
    }
    __syncthreads();

    const int wv = __builtin_amdgcn_readfirstlane(tid >> 6);
    const int c  = tid & 63;
    const int cx = c > 60 ? 60 : c;         // dup lanes clamped, store masked
    const int wr = 4 * kq + wv;             // window row [0,64)

    const float* wbase = W + wr * 1920;     // uniform: 192 K-elems x 10
    const float* srow  = simg + wv * ROWF + cx * CHS;

    float acc[NCLS];
    #pragma unroll
    for (int k = 0; k < NCLS; ++k) acc[k] = 0.f;

    for (int q = 0; q < 24; ++q) {          // 4 pairs per group
        #pragma unroll
        for (int j = 0; j < 4; ++j) {
            const int rem = 8 * q + 2 * j;  // [0,192), even; group never
            const int chq = rem / 48;       // crosses a 48-chunk boundary
            const int uq  = chq * CHS + (rem - 48 * chq);   // uniform, even
            const float2 x = *(const float2*)(srow + uq);   // ds_read_b64
            const float* wp = wbase + rem * 10;             // uniform, 16B-al
            const float4 A0 = *(const float4*)(wp);         // s_load x5
            const float4 A1 = *(const float4*)(wp + 4);
            const float4 A2 = *(const float4*)(wp + 8);
            const float4 A3 = *(const float4*)(wp + 12);
            const float4 A4 = *(const float4*)(wp + 16);
            const float w0[NCLS] = {A0.x,A0.y,A0.z,A0.w,A1.x,A1.y,A1.z,A1.w,A2.x,A2.y};
            const float w1[NCLS] = {A2.z,A2.w,A3.x,A3.y,A3.z,A3.w,A4.x,A4.y,A4.z,A4.w};
            #pragma unroll
            for (int k = 0; k < NCLS; ++k) {
                acc[k] = fmaf(x.x, w0[k], acc[k]);   // v_fmac vacc, sW, vx
                acc[k] = fmaf(x.y, w1[k], acc[k]);
            }
        }
    }

    // ---- store: each wave owns part row (r*64+wr); lane c -> 10 floats ----
    if (c < 61) {
        float* pr = part + (size_t)(r * 64 + wr) * PROW + c * 10;
        #pragma unroll
        for (int k = 0; k < NCLS; k += 2)
            *(float2*)(pr + k) = make_float2(acc[k], acc[k + 1]);
    }
}

// ---------------------------------------------------------------------------
// Kernel 2: sum 64 wr-rows per output row + bias + softmax + prob + mask.
// One block per r: phase 1 coalesced strided sum into LDS, phase 2 softmax.
// ---------------------------------------------------------------------------
__global__ __launch_bounds__(256) void wod_reduce(
    const float* __restrict__ part,   // (61*64, 610)
    const float* __restrict__ bias,   // (10)
    float* __restrict__ out_prob,     // (61,61,10)
    int* __restrict__ mask)           // (10,3721)
{
    __shared__ float lg[PROW];
    const int r   = blockIdx.x;
    const int tid = threadIdx.x;
    const float* pb = part + (size_t)r * 64 * PROW;

    for (int t = tid; t < PROW; t += 256) {
        float s = bias[t - (t / 10) * 10];
        const float* p = pb + t;
        #pragma unroll 8
        for (int wr = 0; wr < 64; ++wr) s += p[wr * PROW];
        lg[t] = s;
    }
    __syncthreads();

    for (int c = tid; c < CG; c += 256) {
        float l[NCLS];
        #pragma unroll
        for (int k = 0; k < NCLS; ++k) l[k] = lg[c * 10 + k];
        float m = -1e30f;
        #pragma unroll
        for (int k = 0; k < NCLS; ++k) m = fmaxf(m, l[k]);
        float ex[NCLS], sm = 0.f;
        #pragma unroll
        for (int k = 0; k < NCLS; ++k) { ex[k] = expf(l[k] - m); sm += ex[k]; }
        const float inv = 1.f / sm;
        const int cell = r * CG + c;
        #pragma unroll
        for (int k = 0; k < NCLS; ++k) {
            const float pr = ex[k] * inv;
            out_prob[cell * 10 + k] = pr;
            mask[k * NP + cell] = (pr > THRESHV) ? 1 : 0;
        }
    }
}

// ---------------------------------------------------------------------------
// Kernel 3: connected components (min-label propagation in LDS) + labels +
// boxes + valid, all fused. One block per class. (Unchanged, proven.)
// ---------------------------------------------------------------------------
__global__ __launch_bounds__(256) void wod_cc(
    const int* __restrict__ mask,     // (10,3721)
    float* __restrict__ out_lbl,      // (61,61,10) as float
    float* __restrict__ out_box,      // (10,3722,4)
    float* __restrict__ out_valid)    // (10,3722)
{
    const int k = blockIdx.x;
    const int tid = threadIdx.x;
    __shared__ int lbl[NP];
    __shared__ int ext0[NSEG], ext1[NSEG];
    __shared__ int changed;

    const int* mk = mask + k * NP;
    for (int idx = tid; idx < NP; idx += 256)
        lbl[idx] = mk[idx] ? (idx + 1) : 0;
    if (tid == 0) changed = 0;
    __syncthreads();

    for (;;) {
        for (int idx = tid; idx < NP; idx += 256) {
            int v = lbl[idx];
            if (v) {
                const int rr = idx / CG;
                const int cc = idx - rr * CG;
                int best = v;
                if (rr > 0)      { int n = lbl[idx - CG]; if (n && n < best) best = n; }
                if (rr < RG - 1) { int n = lbl[idx + CG]; if (n && n < best) best = n; }
                if (cc > 0)      { int n = lbl[idx - 1];  if (n && n < best) best = n; }
                if (cc < CG - 1) { int n = lbl[idx + 1];  if (n && n < best) best = n; }
                if (best < v) { lbl[idx] = best; changed = 1; }
            }
        }
        __syncthreads();
        const bool stop = (changed == 0);
        __syncthreads();           // all reads of `changed` done before reset
        if (stop) break;
        if (tid == 0) changed = 0;
        __syncthreads();
    }

    // labels out (transposed to (r,c,k))
    for (int idx = tid; idx < NP; idx += 256)
        out_lbl[idx * NCLS + k] = (float)lbl[idx];

    float* boxk = out_box + k * NSEG * 4;
    float* valk = out_valid + k * NSEG;

    // pass 1: rmin / cmin
    for (int s2 = tid; s2 < NSEG; s2 += 256) { ext0[s2] = BIGI; ext1[s2] = BIGI; }
    __syncthreads();
    for (int idx = tid; idx < NP; idx += 256) {
        const int v = lbl[idx];
        if (v) {
            const int rr = idx / CG, cc = idx - rr * CG;
            atomicMin(&ext0[v], rr);
            atomicMin(&ext1[v], cc);
        }
    }
    __syncthreads();
    for (int s2 = tid; s2 < NSEG; s2 += 256) {
        const bool valid = (s2 > 0) && (ext0[s2] != BIGI);
        boxk[s2 * 4 + 0] = valid ? (float)(ext0[s2] - 1) : -1.f;
        boxk[s2 * 4 + 1] = valid ? (float)(ext1[s2] - 1) : -1.f;
        valk[s2] = valid ? 1.f : 0.f;
    }
    __syncthreads();

    // pass 2: rmax / cmax
    for (int s2 = tid; s2 < NSEG; s2 += 256) { ext0[s2] = -1; ext1[s2] = -1; }
    __syncthreads();
    for (int idx = tid; idx < NP; idx += 256) {
        const int v = lbl[idx];
        if (v) {
            const int rr = idx / CG, cc = idx - rr * CG;
            atomicMax(&ext0[v], rr);
            atomicMax(&ext1[v], cc);
        }
    }
    __syncthreads();
    for (int s2 = tid; s2 < NSEG; s2 += 256) {
        const bool valid = (s2 > 0) && (ext0[s2] >= 0);
        boxk[s2 * 4 + 2] = valid ? (float)(ext0[s2] + 1) : -1.f;
        boxk[s2 * 4 + 3] = valid ? (float)(ext1[s2] + 1) : -1.f;
    }
}

// ---------------------------------------------------------------------------
extern "C" void kernel_launch(void* const* d_in, const int* in_sizes, int n_in,
                              void* d_out, int out_size, void* d_ws, size_t ws_size,
                              hipStream_t stream) {
    (void)in_sizes; (void)n_in; (void)out_size; (void)ws_size;
    const float* img = (const float*)d_in[0];
    const float* W   = (const float*)d_in[1];
    const float* b   = (const float*)d_in[2];

    float* out       = (float*)d_out;
    float* out_prob  = out;                       // 37210
    float* out_lbl   = out + 37210;               // 37210
    float* out_box   = out + 74420;               // 148880
    float* out_valid = out + 223300;              // 37220

    int*   mask = (int*)d_ws;                        // 10*3721 ints
    float* part = (float*)((int*)d_ws + NCLS * NP);  // 61*64*610 floats ~9.5MB

    hipLaunchKernelGGL(wod_logits_part, dim3(NBLK), dim3(256), 0, stream,
                       img, W, part);
    hipLaunchKernelGGL(wod_reduce, dim3(RG), dim3(256), 0, stream,
                       part, b, out_prob, mask);
    hipLaunchKernelGGL(wod_cc, dim3(NCLS), dim3(256), 0, stream,
                       mask, out_lbl, out_box, out_valid);
}

// Round 13
// 48.350 us; speedup vs baseline: 1.1231x; 1.1231x over previous
//
#include <hip/hip_runtime.h>
#include <math.h>

#define RG 61
#define CG 61
#define NP 3721           // RG*CG
#define NSEG 3722         // NP+1
#define NCLS 10
#define THRESHV 0.7f
#define BIGI 0x3FFFFFFF

#define NKQ 16            // blocks per output row; block covers 4 window rows
#define NBLK (RG*NKQ)     // 976
#define CHS 51            // ODD chunk stride: img banks 19c mod 32 -> <=2-way
#define ROWF (64*CHS)     // 3264 floats per staged row
#define PROW 640          // part row: 64 col-slots x 10 classes (61 used)

// constant-address-space view of W: uniform scalar loads -> s_load into SGPRs
typedef __attribute__((address_space(4))) const float cfl;

// ---------------------------------------------------------------------------
// Kernel 1: partial logits, wave-uniform W via SCALAR loads.
// Block (r,kq) covers window rows 4kq..4kq+3 (wave wv owns row wr=4kq+wv).
// All 64 lanes of a wave share one k-pair: the 20 W floats are wave-uniform.
// W is read ELEMENT-WISE through address_space(4) (fix for round-12 compile
// error: HIP float4 ctor can't bind an AS4 reference); the compiler merges
// the 20 uniform scalar loads into s_load_dwordx16 + s_load_dwordx4.
// Lane = patch column c (61 used). Img rows staged chunked [ch][CHS=51]:
// per pair ONE ds_read2_b32 (banks 19c distinct -> <=2-way).
// Per pair: 20 v_fmac (sgpr x vgpr) + 1 LDS instr. LDS-pipe demand/CU ~10Kcy
// << VALU span ~14.6Kcy -> VALU-bound. 52.2KB LDS -> 3 blocks/CU.
// Waves block-sum their 4 partials in LDS -> part rows = 16 per r (2.5MB).
// ---------------------------------------------------------------------------
__global__ __launch_bounds__(256, 3) void wod_logits_part(
    const float* __restrict__ img,   // (1024,1024,3)
    const float* __restrict__ W,     // (12288,10)
    float* __restrict__ part)        // (61*16, 640)
{
    __shared__ float simg[4 * ROWF]; // 52224 B
    const int tid = threadIdx.x;
    // bijective XCD swizzle: 976 = 8*122
    const int o  = (blockIdx.x & 7) * 122 + (blockIdx.x >> 3);
    const int r  = o >> 4;           // output row  [0,61)
    const int kq = o & 15;           // row-quad    [0,16)
    const int R0 = 16 * r + 4 * kq;  // first image row

    // ---- stage 4 image rows, chunked [ch][CHS] ----
    for (int u = tid; u < 3072; u += 256) {
        const int row = u / 768;
        const int v   = u - row * 768;
        const int p0  = v * 4;
        const float4 x4 = *(const float4*)(img + (size_t)(R0 + row) * 3072 + p0);
        const int ch = p0 / 48;             // p0%48 in {0,..,44}: never crosses
        float* d = simg + row * ROWF + ch * CHS + (p0 - ch * 48);
        d[0] = x4.x; d[1] = x4.y; d[2] = x4.z; d[3] = x4.w;
    }
    __syncthreads();

    const int wv = __builtin_amdgcn_readfirstlane(tid >> 6);  // uniform wave id
    const int c  = tid & 63;
    const int cx = c > 60 ? 60 : c;         // dup lanes clamped (ignored later)
    const int wr = 4 * kq + wv;             // window row [0,64)

    const cfl*   wbase = (const cfl*)W + wr * 1920;   // uniform
    const float* srow  = simg + wv * ROWF + cx * CHS;

    float acc[NCLS];
    #pragma unroll
    for (int k = 0; k < NCLS; ++k) acc[k] = 0.f;

    #pragma unroll 1
    for (int cc2 = 0; cc2 < 4; ++cc2) {     // 48-element chunk quarter
        const float* sch = srow + cc2 * CHS;
        const cfl*   wch = wbase + cc2 * 480;
        #pragma unroll
        for (int q6 = 0; q6 < 6; ++q6) {
            #pragma unroll
            for (int j = 0; j < 4; ++j) {
                const int le = q6 * 8 + 2 * j;        // even, [0,48)
                const float xx = sch[le];             // ds_read2_b32
                const float xy = sch[le + 1];
                const cfl* wp = wch + le * 10;        // uniform scalar loads
                float w_[20];
                #pragma unroll
                for (int k = 0; k < 20; ++k) w_[k] = wp[k];   // -> s_load x16+x4
                #pragma unroll
                for (int k = 0; k < NCLS; ++k) {
                    acc[k] = fmaf(xx, w_[k],      acc[k]);   // v_fmac v, s, v
                    acc[k] = fmaf(xy, w_[k + 10], acc[k]);
                }
            }
        }
    }

    // ---- block-sum the 4 waves' partials in LDS (reuse simg) ----
    __syncthreads();                 // all waves done reading simg
    float* scratch = simg;           // (4 x PROW)
    {
        float* sc = scratch + wv * PROW + c * 10;
        #pragma unroll
        for (int k = 0; k < NCLS; ++k) sc[k] = acc[k];
    }
    __syncthreads();
    for (int t = tid; t < PROW; t += 256)
        part[(size_t)o * PROW + t] = scratch[t] + scratch[PROW + t]
                                   + scratch[2 * PROW + t] + scratch[3 * PROW + t];
}

// ---------------------------------------------------------------------------
// Kernel 2: sum 16 kq-slices + bias + softmax + prob + mask. Block per r.
// ---------------------------------------------------------------------------
__global__ __launch_bounds__(256) void wod_reduce(
    const float* __restrict__ part,   // (61*16, 640)
    const float* __restrict__ bias,   // (10)
    float* __restrict__ out_prob,     // (61,61,10)
    int* __restrict__ mask)           // (10,3721)
{
    __shared__ float lg[PROW];
    const int r   = blockIdx.x;
    const int tid = threadIdx.x;
    const float* pb = part + (size_t)r * NKQ * PROW;

    for (int t = tid; t < PROW; t += 256) {
        float s = bias[t - (t / 10) * 10];
        #pragma unroll 4
        for (int kq = 0; kq < NKQ; ++kq) s += pb[kq * PROW + t];
        lg[t] = s;
    }
    __syncthreads();

    for (int c = tid; c < CG; c += 256) {
        float l[NCLS];
        #pragma unroll
        for (int k = 0; k < NCLS; ++k) l[k] = lg[c * 10 + k];
        float m = -1e30f;
        #pragma unroll
        for (int k = 0; k < NCLS; ++k) m = fmaxf(m, l[k]);
        float ex[NCLS], sm = 0.f;
        #pragma unroll
        for (int k = 0; k < NCLS; ++k) { ex[k] = expf(l[k] - m); sm += ex[k]; }
        const float inv = 1.f / sm;
        const int cell = r * CG + c;
        #pragma unroll
        for (int k = 0; k < NCLS; ++k) {
            const float pr = ex[k] * inv;
            out_prob[cell * 10 + k] = pr;
            mask[k * NP + cell] = (pr > THRESHV) ? 1 : 0;
        }
    }
}

// ---------------------------------------------------------------------------
// Kernel 3: connected components (min-label propagation in LDS) + labels +
// boxes + valid, all fused. One block per class. (Unchanged, proven.)
// ---------------------------------------------------------------------------
__global__ __launch_bounds__(256) void wod_cc(
    const int* __restrict__ mask,     // (10,3721)
    float* __restrict__ out_lbl,      // (61,61,10) as float
    float* __restrict__ out_box,      // (10,3722,4)
    float* __restrict__ out_valid)    // (10,3722)
{
    const int k = blockIdx.x;
    const int tid = threadIdx.x;
    __shared__ int lbl[NP];
    __shared__ int ext0[NSEG], ext1[NSEG];
    __shared__ int changed;

    const int* mk = mask + k * NP;
    for (int idx = tid; idx < NP; idx += 256)
        lbl[idx] = mk[idx] ? (idx + 1) : 0;
    if (tid == 0) changed = 0;
    __syncthreads();

    for (;;) {
        for (int idx = tid; idx < NP; idx += 256) {
            int v = lbl[idx];
            if (v) {
                const int rr = idx / CG;
                const int cc = idx - rr * CG;
                int best = v;
                if (rr > 0)      { int n = lbl[idx - CG]; if (n && n < best) best = n; }
                if (rr < RG - 1) { int n = lbl[idx + CG]; if (n && n < best) best = n; }
                if (cc > 0)      { int n = lbl[idx - 1];  if (n && n < best) best = n; }
                if (cc < CG - 1) { int n = lbl[idx + 1];  if (n && n < best) best = n; }
                if (best < v) { lbl[idx] = best; changed = 1; }
            }
        }
        __syncthreads();
        const bool stop = (changed == 0);
        __syncthreads();           // all reads of `changed` done before reset
        if (stop) break;
        if (tid == 0) changed = 0;
        __syncthreads();
    }

    // labels out (transposed to (r,c,k))
    for (int idx = tid; idx < NP; idx += 256)
        out_lbl[idx * NCLS + k] = (float)lbl[idx];

    float* boxk = out_box + k * NSEG * 4;
    float* valk = out_valid + k * NSEG;

    // pass 1: rmin / cmin
    for (int s2 = tid; s2 < NSEG; s2 += 256) { ext0[s2] = BIGI; ext1[s2] = BIGI; }
    __syncthreads();
    for (int idx = tid; idx < NP; idx += 256) {
        const int v = lbl[idx];
        if (v) {
            const int rr = idx / CG, cc = idx - rr * CG;
            atomicMin(&ext0[v], rr);
            atomicMin(&ext1[v], cc);
        }
    }
    __syncthreads();
    for (int s2 = tid; s2 < NSEG; s2 += 256) {
        const bool valid = (s2 > 0) && (ext0[s2] != BIGI);
        boxk[s2 * 4 + 0] = valid ? (float)(ext0[s2] - 1) : -1.f;
        boxk[s2 * 4 + 1] = valid ? (float)(ext1[s2] - 1) : -1.f;
        valk[s2] = valid ? 1.f : 0.f;
    }
    __syncthreads();

    // pass 2: rmax / cmax
    for (int s2 = tid; s2 < NSEG; s2 += 256) { ext0[s2] = -1; ext1[s2] = -1; }
    __syncthreads();
    for (int idx = tid; idx < NP; idx += 256) {
        const int v = lbl[idx];
        if (v) {
            const int rr = idx / CG, cc = idx - rr * CG;
            atomicMax(&ext0[v], rr);
            atomicMax(&ext1[v], cc);
        }
    }
    __syncthreads();
    for (int s2 = tid; s2 < NSEG; s2 += 256) {
        const bool valid = (s2 > 0) && (ext0[s2] >= 0);
        boxk[s2 * 4 + 2] = valid ? (float)(ext0[s2] + 1) : -1.f;
        boxk[s2 * 4 + 3] = valid ? (float)(ext1[s2] + 1) : -1.f;
    }
}

// ---------------------------------------------------------------------------
extern "C" void kernel_launch(void* const* d_in, const int* in_sizes, int n_in,
                              void* d_out, int out_size, void* d_ws, size_t ws_size,
                              hipStream_t stream) {
    (void)in_sizes; (void)n_in; (void)out_size; (void)ws_size;
    const float* img = (const float*)d_in[0];
    const float* W   = (const float*)d_in[1];
    const float* b   = (const float*)d_in[2];

    float* out       = (float*)d_out;
    float* out_prob  = out;                       // 37210
    float* out_lbl   = out + 37210;               // 37210
    float* out_box   = out + 74420;               // 148880
    float* out_valid = out + 223300;              // 37220

    int*   mask = (int*)d_ws;                        // 10*3721 ints
    float* part = (float*)((int*)d_ws + NCLS * NP);  // 976*640 floats ~2.5MB

    hipLaunchKernelGGL(wod_logits_part, dim3(NBLK), dim3(256), 0, stream,
                       img, W, part);
    hipLaunchKernelGGL(wod_reduce, dim3(RG), dim3(256), 0, stream,
                       part, b, out_prob, mask);
    hipLaunchKernelGGL(wod_cc, dim3(NCLS), dim3(256), 0, stream,
                       mask, out_lbl, out_box, out_valid);
}